// Round 6
// baseline (284.243 us; speedup 1.0000x reference)
//
#include <hip/hip_runtime.h>
#include <stdint.h>

// Recall over [B=32, F=512, T=2048]:
//   p_adj[b,f,t] = predicted[b, f==0?1:f, t==0?1:t]
//   out = sum(p_adj * (gt!=0)) / count(gt!=0), or 0 if count==0.
//
// R6: LDS-staged streaming via global_load_lds. R1-R5 established the kernel
// is limited by outstanding-load capacity per CU when loads target VGPRs
// (~14.6 cy/line; compiler collapses any prefetch pack). global_load_lds is
// fire-and-forget (vmcnt-tracked, no dest register), demonstrated at
// ~2.9 cy/line in the m97 GEMM staging loop. Each wave issues 8 x 1KB
// stage requests per iteration; 4-5 blocks/CU overlap stage/consume phases.

constexpr int B_ = 32;
constexpr int F_ = 512;
constexpr int T_ = 2048;
constexpr long long NTOT = (long long)B_ * F_ * T_;   // 2^25
constexpr int BLK   = 256;                            // 4 waves
constexpr int NBLK  = 1024;
constexpr int CHUNK = 4096;                           // elements/array/iter/block
constexpr int ITERS = 8;
static_assert((long long)NBLK * CHUNK * ITERS == NTOT, "exact cover");

constexpr int EDGE_ITEMS = B_ * T_ + B_ * F_;         // 81,920
constexpr int EDGE_BLKS  = EDGE_ITEMS / BLK;          // 320

typedef const __attribute__((address_space(1))) void* gvp;
typedef __attribute__((address_space(3))) void* lvp;

// ---------------- block reduction helper ----------------
__device__ __forceinline__ void block_reduce(float& s, int& c) {
    #pragma unroll
    for (int off = 32; off > 0; off >>= 1) {
        s += __shfl_down(s, off, 64);
        c += __shfl_down(c, off, 64);
    }
    __shared__ float ss[4];
    __shared__ int   sc[4];
    int lane = threadIdx.x & 63, wave = threadIdx.x >> 6;
    if (lane == 0) { ss[wave] = s; sc[wave] = c; }
    __syncthreads();
    if (threadIdx.x == 0) {
        s = ss[0] + ss[1] + ss[2] + ss[3];
        c = sc[0] + sc[1] + sc[2] + sc[3];
    }
}

// ---------------- main: LDS-staged masked sum ----------------
__global__ __launch_bounds__(256) void recall_main(
    const float* __restrict__ pred,
    const int* __restrict__ gt,
    float* __restrict__ bsum,
    unsigned int* __restrict__ bcnt)
{
    __shared__ float ps[CHUNK];   // 16 KB
    __shared__ int   gs[CHUNK];   // 16 KB

    const int t    = threadIdx.x;
    const int lane = t & 63;
    const int wave = t >> 6;
    const size_t block_base = (size_t)blockIdx.x * ((size_t)CHUNK * ITERS);

    float lsum = 0.f;
    int   lcnt = 0;

    for (int it = 0; it < ITERS; ++it) {
        const size_t chunk = block_base + (size_t)it * CHUNK;

        // Stage: wave w covers elements [w*1024, (w+1)*1024) of the chunk.
        // Each global_load_lds: 64 lanes x 16B = 1KB, LDS dest is the
        // wave-uniform base + lane*16 (contiguous - layout matches source).
        #pragma unroll
        for (int k = 0; k < 4; ++k) {
            size_t e = chunk + (size_t)wave * 1024 + (size_t)k * 256 + (size_t)lane * 4;
            __builtin_amdgcn_global_load_lds(
                (gvp)(pred + e), (lvp)(&ps[wave * 1024 + k * 256]), 16, 0, 0);
            __builtin_amdgcn_global_load_lds(
                (gvp)(gt + e),   (lvp)(&gs[wave * 1024 + k * 256]), 16, 0, 0);
        }
        __syncthreads();   // drains vmcnt; LDS chunk complete for all waves

        // Consume: 1024 quads in LDS, thread t takes quads t, t+256, ...
        const float4* p4 = (const float4*)ps;
        const int4*   g4 = (const int4*)gs;
        #pragma unroll
        for (int j = 0; j < 4; ++j) {
            float4 p = p4[t + j * 256];
            int4   g = g4[t + j * 256];
            lcnt += (g.x != 0) + (g.y != 0) + (g.z != 0) + (g.w != 0);
            lsum += (g.x ? p.x : 0.f);
            lsum += (g.y ? p.y : 0.f);
            lsum += (g.z ? p.z : 0.f);
            lsum += (g.w ? p.w : 0.f);
        }
        __syncthreads();   // all reads done before next iter's staging lands
    }

    block_reduce(lsum, lcnt);
    if (threadIdx.x == 0) {
        bsum[blockIdx.x] = lsum;
        bcnt[blockIdx.x] = (unsigned int)lcnt;
    }
}

// ---------------- edge-remap correction ----------------
// Items [0, B*T):          f==0 row  (all t; remap f->1, t->max(t,1))
// Items [B*T, B*T + B*F):  t==0 col, f>=1 only (remap t->1); f==0 cell
// is covered by the first range.
__global__ __launch_bounds__(256) void recall_edge(
    const float* __restrict__ pred,
    const int* __restrict__ gt,
    float* __restrict__ csum)
{
    unsigned idx = blockIdx.x * BLK + threadIdx.x;
    float corr = 0.f;
    if (idx < (unsigned)(B_ * T_)) {
        unsigned b = idx >> 11, t = idx & (T_ - 1);
        unsigned raw = (b << 20) | t;
        unsigned tp  = (t == 0u) ? 1u : t;
        unsigned adj = (b << 20) | (1u << 11) | tp;
        if (gt[raw]) corr = pred[adj] - pred[raw];
    } else {
        unsigned i2 = idx - (unsigned)(B_ * T_);
        unsigned b = i2 >> 9, f = i2 & (F_ - 1);
        if (f != 0u) {
            unsigned raw = (b << 20) | (f << 11);
            if (gt[raw]) corr = pred[raw + 1] - pred[raw];
        }
    }
    int dummy = 0;
    block_reduce(corr, dummy);
    if (threadIdx.x == 0) csum[blockIdx.x] = corr;
}

// ---------------- finalize ----------------
__global__ __launch_bounds__(256) void recall_fin(
    const float* __restrict__ bsum,
    const unsigned int* __restrict__ bcnt,
    const float* __restrict__ csum,
    float* __restrict__ out)
{
    float s = 0.f;
    int   c = 0;
    for (int j = threadIdx.x; j < NBLK; j += BLK) {
        s += bsum[j];
        c += (int)bcnt[j];
    }
    for (int j = threadIdx.x; j < EDGE_BLKS; j += BLK) s += csum[j];

    block_reduce(s, c);
    if (threadIdx.x == 0)
        out[0] = (c > 0) ? (s / (float)c) : 0.0f;
}

extern "C" void kernel_launch(void* const* d_in, const int* in_sizes, int n_in,
                              void* d_out, int out_size, void* d_ws, size_t ws_size,
                              hipStream_t stream)
{
    const float* pred = (const float*)d_in[0];
    const int*   gt   = (const int*)d_in[1];
    float*       out  = (float*)d_out;

    float*        bsum = (float*)d_ws;
    unsigned int* bcnt = (unsigned int*)((char*)d_ws + NBLK * sizeof(float));
    float*        csum = (float*)((char*)d_ws + 2 * NBLK * sizeof(float));

    recall_main<<<NBLK, BLK, 0, stream>>>(pred, gt, bsum, bcnt);
    recall_edge<<<EDGE_BLKS, BLK, 0, stream>>>(pred, gt, csum);
    recall_fin<<<1, BLK, 0, stream>>>(bsum, bcnt, csum, out);
}

// Round 8
// 256.313 us; speedup vs baseline: 1.1090x; 1.1090x over previous
//
#include <hip/hip_runtime.h>

// Recall over [B=32, F=512, T=2048]:
//   p_adj[b,f,t] = predicted[b, f==0?1:f, t==0?1:t]
//   out = sum(p_adj * (gt!=0)) / count(gt!=0), or 0 if count==0.
//
// R8 (= R7 with compile fix): __builtin_nontemporal_load requires native
// clang vector types, not HIP_vector_type — use ext_vector_type(4).
// (1) nontemporal loads: this stream can never hit the 32KB L1, so skip L1
// allocation/replay per line; (2) single-resident-round grid: 2048 blocks
// x 256thr = 8 blocks/CU = 32 waves/CU all co-resident. Contiguous tiling
// from R5: block = 64KB/array, wave = 16KB/array, each k a coalesced 1KB.

constexpr int B_ = 32;
constexpr int F_ = 512;
constexpr int T_ = 2048;
constexpr long long NTOT = (long long)B_ * F_ * T_;   // 2^25
constexpr int NQ      = (int)(NTOT >> 2);             // 8,388,608 quads
constexpr int BLK     = 256;
constexpr int NBLK    = 2048;                         // 8 blocks/CU, 1 round
constexpr int QPB     = NQ / NBLK;                    // 4096 quads per block
constexpr int QPW     = QPB / 4;                      // 1024 quads per wave
constexpr int PER_THR = QPW / 64;                     // 16 quads per thread
static_assert((long long)NBLK * QPB == NQ, "exact cover");

constexpr int EDGE_ITEMS = B_ * T_ + B_ * F_;         // 81,920
constexpr int EDGE_BLKS  = EDGE_ITEMS / BLK;          // 320

typedef float vf4 __attribute__((ext_vector_type(4)));
typedef int   vi4 __attribute__((ext_vector_type(4)));

// ---------------- block reduction helper ----------------
__device__ __forceinline__ void block_reduce(float& s, int& c) {
    #pragma unroll
    for (int off = 32; off > 0; off >>= 1) {
        s += __shfl_down(s, off, 64);
        c += __shfl_down(c, off, 64);
    }
    __shared__ float ss[4];
    __shared__ int   sc[4];
    int lane = threadIdx.x & 63, wave = threadIdx.x >> 6;
    if (lane == 0) { ss[wave] = s; sc[wave] = c; }
    __syncthreads();
    if (threadIdx.x == 0) {
        s = ss[0] + ss[1] + ss[2] + ss[3];
        c = sc[0] + sc[1] + sc[2] + sc[3];
    }
}

// ---------------- main branchless masked sum ----------------
__global__ __launch_bounds__(256) void recall_main(
    const vf4* __restrict__ p4,
    const vi4* __restrict__ g4,
    float* __restrict__ bsum,
    unsigned int* __restrict__ bcnt)
{
    const unsigned lane = threadIdx.x & 63;
    const unsigned wave = threadIdx.x >> 6;
    const size_t base = (size_t)blockIdx.x * QPB + (size_t)wave * QPW + lane;

    float lsum = 0.f;
    int   lcnt = 0;

    #pragma unroll
    for (int k = 0; k < PER_THR; ++k) {
        size_t q = base + (size_t)k * 64;
        vf4 p = __builtin_nontemporal_load(&p4[q]);
        vi4 g = __builtin_nontemporal_load(&g4[q]);
        lcnt += (g.x != 0) + (g.y != 0) + (g.z != 0) + (g.w != 0);
        lsum += (g.x ? p.x : 0.f);
        lsum += (g.y ? p.y : 0.f);
        lsum += (g.z ? p.z : 0.f);
        lsum += (g.w ? p.w : 0.f);
    }

    block_reduce(lsum, lcnt);
    if (threadIdx.x == 0) {
        bsum[blockIdx.x] = lsum;
        bcnt[blockIdx.x] = (unsigned int)lcnt;
    }
}

// ---------------- edge-remap correction ----------------
// Items [0, B*T):          f==0 row  (all t; remap f->1, t->max(t,1))
// Items [B*T, B*T + B*F):  t==0 col, f>=1 only (remap t->1); f==0 cell
// is covered by the first range.
__global__ __launch_bounds__(256) void recall_edge(
    const float* __restrict__ pred,
    const int* __restrict__ gt,
    float* __restrict__ csum)
{
    unsigned idx = blockIdx.x * BLK + threadIdx.x;
    float corr = 0.f;
    if (idx < (unsigned)(B_ * T_)) {
        unsigned b = idx >> 11, t = idx & (T_ - 1);
        unsigned raw = (b << 20) | t;
        unsigned tp  = (t == 0u) ? 1u : t;
        unsigned adj = (b << 20) | (1u << 11) | tp;
        if (gt[raw]) corr = pred[adj] - pred[raw];
    } else {
        unsigned i2 = idx - (unsigned)(B_ * T_);
        unsigned b = i2 >> 9, f = i2 & (F_ - 1);
        if (f != 0u) {
            unsigned raw = (b << 20) | (f << 11);
            if (gt[raw]) corr = pred[raw + 1] - pred[raw];
        }
    }
    int dummy = 0;
    block_reduce(corr, dummy);
    if (threadIdx.x == 0) csum[blockIdx.x] = corr;
}

// ---------------- finalize ----------------
__global__ __launch_bounds__(256) void recall_fin(
    const float* __restrict__ bsum,
    const unsigned int* __restrict__ bcnt,
    const float* __restrict__ csum,
    float* __restrict__ out)
{
    float s = 0.f;
    int   c = 0;
    for (int j = threadIdx.x; j < NBLK; j += BLK) {
        s += bsum[j];
        c += (int)bcnt[j];
    }
    for (int j = threadIdx.x; j < EDGE_BLKS; j += BLK) s += csum[j];

    block_reduce(s, c);
    if (threadIdx.x == 0)
        out[0] = (c > 0) ? (s / (float)c) : 0.0f;
}

extern "C" void kernel_launch(void* const* d_in, const int* in_sizes, int n_in,
                              void* d_out, int out_size, void* d_ws, size_t ws_size,
                              hipStream_t stream)
{
    const float* pred = (const float*)d_in[0];
    const int*   gt   = (const int*)d_in[1];
    float*       out  = (float*)d_out;

    float*        bsum = (float*)d_ws;
    unsigned int* bcnt = (unsigned int*)((char*)d_ws + NBLK * sizeof(float));
    float*        csum = (float*)((char*)d_ws + 2 * NBLK * sizeof(float));

    recall_main<<<NBLK, BLK, 0, stream>>>((const vf4*)pred, (const vi4*)gt,
                                          bsum, bcnt);
    recall_edge<<<EDGE_BLKS, BLK, 0, stream>>>(pred, gt, csum);
    recall_fin<<<1, BLK, 0, stream>>>(bsum, bcnt, csum, out);
}

// Round 9
// 255.114 us; speedup vs baseline: 1.1142x; 1.0047x over previous
//
#include <hip/hip_runtime.h>

// Recall over [B=32, F=512, T=2048]:
//   p_adj[b,f,t] = predicted[b, f==0?1:f, t==0?1:t]
//   out = sum(p_adj * (gt!=0)) / count(gt!=0), or 0 if count==0.
//
// R9: edge correction fused into the main streaming kernel (40 scattered
// edge items per block), descending block->data mapping (read most-recently
// -written regions first for Infinity-Cache recency), nt loads + single
// -resident-round grid kept from R8. Structure: 2048 blocks x 256 thr =
// 8 blocks/CU = 32 waves/CU, block covers contiguous 64KB per array.

constexpr int B_ = 32;
constexpr int F_ = 512;
constexpr int T_ = 2048;
constexpr long long NTOT = (long long)B_ * F_ * T_;   // 2^25
constexpr int NQ      = (int)(NTOT >> 2);             // 8,388,608 quads
constexpr int BLK     = 256;
constexpr int NBLK    = 2048;                         // 8 blocks/CU, 1 round
constexpr int QPB     = NQ / NBLK;                    // 4096 quads per block
constexpr int QPW     = QPB / 4;                      // 1024 quads per wave
constexpr int PER_THR = QPW / 64;                     // 16 quads per thread
static_assert((long long)NBLK * QPB == NQ, "exact cover");

constexpr int EDGE_ITEMS   = B_ * T_ + B_ * F_;       // 81,920
constexpr int EDGE_PER_BLK = EDGE_ITEMS / NBLK;       // 40
static_assert(EDGE_PER_BLK * NBLK == EDGE_ITEMS, "exact edge cover");

typedef float vf4 __attribute__((ext_vector_type(4)));
typedef int   vi4 __attribute__((ext_vector_type(4)));

// ---------------- block reduction helper ----------------
__device__ __forceinline__ void block_reduce(float& s, int& c) {
    #pragma unroll
    for (int off = 32; off > 0; off >>= 1) {
        s += __shfl_down(s, off, 64);
        c += __shfl_down(c, off, 64);
    }
    __shared__ float ss[4];
    __shared__ int   sc[4];
    int lane = threadIdx.x & 63, wave = threadIdx.x >> 6;
    if (lane == 0) { ss[wave] = s; sc[wave] = c; }
    __syncthreads();
    if (threadIdx.x == 0) {
        s = ss[0] + ss[1] + ss[2] + ss[3];
        c = sc[0] + sc[1] + sc[2] + sc[3];
    }
}

// ---------------- main: streaming masked sum + fused edge correction ------
__global__ __launch_bounds__(256) void recall_main(
    const float* __restrict__ pred,
    const int* __restrict__ gt,
    float* __restrict__ bsum,
    unsigned int* __restrict__ bcnt)
{
    const unsigned lane = threadIdx.x & 63;
    const unsigned wave = threadIdx.x >> 6;
    // Descending data mapping: block 0 reads the highest addresses (written
    // most recently by the harness restore/poison) first.
    const unsigned db = (unsigned)(NBLK - 1) - blockIdx.x;
    const size_t base = (size_t)db * QPB + (size_t)wave * QPW + lane;

    const vf4* p4 = (const vf4*)pred;
    const vi4* g4 = (const vi4*)gt;

    float lsum = 0.f;
    int   lcnt = 0;

    // Fused edge-remap correction: 40 items per block, threads 0..39.
    //   item < B*T:          f==0 row (b,t): remap f->1, t->max(t,1)
    //   item >= B*T:         t==0 col, f>=1: remap t->1 (f==0,t==0 already
    //                        covered by the first range)
    // corr = p[adj] - p[raw] at gt-nonzero positions; count is unchanged.
    if (threadIdx.x < EDGE_PER_BLK) {
        unsigned idx = blockIdx.x * EDGE_PER_BLK + threadIdx.x;
        if (idx < (unsigned)(B_ * T_)) {
            unsigned b = idx >> 11, t = idx & (T_ - 1);
            unsigned raw = (b << 20) | t;
            unsigned tp  = (t == 0u) ? 1u : t;
            unsigned adj = (b << 20) | (1u << 11) | tp;
            if (gt[raw]) lsum += pred[adj] - pred[raw];
        } else {
            unsigned i2 = idx - (unsigned)(B_ * T_);
            unsigned b = i2 >> 9, f = i2 & (F_ - 1);
            if (f != 0u) {
                unsigned raw = (b << 20) | (f << 11);
                if (gt[raw]) lsum += pred[raw + 1] - pred[raw];
            }
        }
    }

    // Streaming masked sum over this block's contiguous 64KB/array chunk.
    #pragma unroll
    for (int k = 0; k < PER_THR; ++k) {
        size_t q = base + (size_t)k * 64;
        vf4 p = __builtin_nontemporal_load(&p4[q]);
        vi4 g = __builtin_nontemporal_load(&g4[q]);
        lcnt += (g.x != 0) + (g.y != 0) + (g.z != 0) + (g.w != 0);
        lsum += (g.x ? p.x : 0.f);
        lsum += (g.y ? p.y : 0.f);
        lsum += (g.z ? p.z : 0.f);
        lsum += (g.w ? p.w : 0.f);
    }

    block_reduce(lsum, lcnt);
    if (threadIdx.x == 0) {
        bsum[blockIdx.x] = lsum;
        bcnt[blockIdx.x] = (unsigned int)lcnt;
    }
}

// ---------------- finalize ----------------
__global__ __launch_bounds__(256) void recall_fin(
    const float* __restrict__ bsum,
    const unsigned int* __restrict__ bcnt,
    float* __restrict__ out)
{
    float s = 0.f;
    int   c = 0;
    for (int j = threadIdx.x; j < NBLK; j += BLK) {
        s += bsum[j];
        c += (int)bcnt[j];
    }
    block_reduce(s, c);
    if (threadIdx.x == 0)
        out[0] = (c > 0) ? (s / (float)c) : 0.0f;
}

extern "C" void kernel_launch(void* const* d_in, const int* in_sizes, int n_in,
                              void* d_out, int out_size, void* d_ws, size_t ws_size,
                              hipStream_t stream)
{
    const float* pred = (const float*)d_in[0];
    const int*   gt   = (const int*)d_in[1];
    float*       out  = (float*)d_out;

    float*        bsum = (float*)d_ws;
    unsigned int* bcnt = (unsigned int*)((char*)d_ws + NBLK * sizeof(float));

    recall_main<<<NBLK, BLK, 0, stream>>>(pred, gt, bsum, bcnt);
    recall_fin<<<1, BLK, 0, stream>>>(bsum, bcnt, out);
}